// Round 1
// baseline (221.371 us; speedup 1.0000x reference)
//
#include <hip/hip_runtime.h>
#include <math.h>

// Problem constants (B, N, C, T, H, G) = (8, 256, 128, 64, 4, 12), D = 32
namespace {
constexpr int kB = 8, kN = 256, kC = 128, kT = 64, kH = 4, kG = 12, kD = 32;
constexpr float kEps = 1e-6f;
constexpr float kInvSqrtC = 0.08838834764831845f;   // 1/sqrt(128)
constexpr float kInvSqrtD = 0.17677669529663687f;   // 1/sqrt(32)

// workspace layout (float offsets)
constexpr int WS_Q     = 0;                          // [b][n][c]
constexpr int WS_K     = WS_Q + kB*kN*kC;            // [b][n][c]
constexpr int WS_V     = WS_K + kB*kN*kC;            // [b][n][c]
constexpr int WS_SIZES = WS_V + kB*kN*kC;            // [b][n][3]
constexpr int WS_KTXT  = WS_SIZES + kB*kN*3;         // [b][t][c]
constexpr int WS_VTXT  = WS_KTXT + kB*kT*kC;         // [b][t][c]
constexpr int WS_WKF   = WS_VTXT + kB*kT*kC;         // [b][g][t] = Wrel @ k_txt^T
constexpr int WS_SK    = WS_WKF + kB*kG*kT;          // [b][t]    = brel . k_txt[t]
constexpr int WS_VB    = WS_SK + kB*kT;              // [b][t][h] = v_txt @ Wbias
constexpr int WS_WB1   = WS_VB + kB*kT*kH;           // [g][h]    = Wrel @ Wbias
constexpr int WS_CB    = WS_WB1 + kG*kH;             // [h]       = brel@Wbias + bbias
}

// ---------------------------------------------------------------------------
// Kernel 1: fused linear projections.
//   blocks [0, B*N)      : q/k/v = feat @ Wq/Wk/Wv + b
//   blocks [B*N, +B*T)   : k_txt/v_txt = lang @ Wtk/Wtv + b
// ---------------------------------------------------------------------------
static __global__ __launch_bounds__(128)
void proj_kernel(const float* __restrict__ feat, const float* __restrict__ lang,
                 const float* __restrict__ Wq, const float* __restrict__ bq,
                 const float* __restrict__ Wk, const float* __restrict__ bk,
                 const float* __restrict__ Wv, const float* __restrict__ bv,
                 const float* __restrict__ Wtk, const float* __restrict__ btk,
                 const float* __restrict__ Wtv, const float* __restrict__ btv,
                 float* __restrict__ ws)
{
  const int blk = blockIdx.x;
  const int c = threadIdx.x;
  __shared__ float row[kC];
  if (blk < kB*kN) {
    row[c] = feat[(size_t)blk*kC + c];
    __syncthreads();
    float aq = bq[c], ak = bk[c], av = bv[c];
#pragma unroll 8
    for (int d = 0; d < kC; ++d) {
      const float fv = row[d];
      aq = fmaf(fv, Wq[d*kC + c], aq);
      ak = fmaf(fv, Wk[d*kC + c], ak);
      av = fmaf(fv, Wv[d*kC + c], av);
    }
    ws[WS_Q + blk*kC + c] = aq;
    ws[WS_K + blk*kC + c] = ak;
    ws[WS_V + blk*kC + c] = av;
  } else {
    const int r = blk - kB*kN;          // 0 .. B*T-1
    row[c] = lang[(size_t)r*kC + c];
    __syncthreads();
    float akt = btk[c], avt = btv[c];
#pragma unroll 8
    for (int d = 0; d < kC; ++d) {
      const float fv = row[d];
      akt = fmaf(fv, Wtk[d*kC + c], akt);
      avt = fmaf(fv, Wtv[d*kC + c], avt);
    }
    ws[WS_KTXT + r*kC + c] = akt;
    ws[WS_VTXT + r*kC + c] = avt;
  }
}

// ---------------------------------------------------------------------------
// Kernel 2: per-batch algebraic folds + box sizes. Grid = B blocks x 256 thr.
// ---------------------------------------------------------------------------
static __global__ __launch_bounds__(256)
void fold_kernel(const float* __restrict__ corners,
                 const float* __restrict__ Wrel, const float* __restrict__ brel,
                 const float* __restrict__ Wbias, const float* __restrict__ bbias,
                 float* __restrict__ ws)
{
  const int b = blockIdx.x;
  const int tid = threadIdx.x;

  // sizes[b][n][ax] = max - min over 8 corners
  {
    const int n = tid;
    const float* cp = corners + ((size_t)(b*kN + n))*8*3;
    float mn0 = cp[0], mn1 = cp[1], mn2 = cp[2];
    float mx0 = mn0, mx1 = mn1, mx2 = mn2;
#pragma unroll
    for (int k = 1; k < 8; ++k) {
      const float v0 = cp[k*3+0], v1 = cp[k*3+1], v2 = cp[k*3+2];
      mn0 = fminf(mn0, v0); mx0 = fmaxf(mx0, v0);
      mn1 = fminf(mn1, v1); mx1 = fmaxf(mx1, v1);
      mn2 = fminf(mn2, v2); mx2 = fmaxf(mx2, v2);
    }
    ws[WS_SIZES + (b*kN + n)*3 + 0] = mx0 - mn0;
    ws[WS_SIZES + (b*kN + n)*3 + 1] = mx1 - mn1;
    ws[WS_SIZES + (b*kN + n)*3 + 2] = mx2 - mn2;
  }

  const float* ktxt = ws + WS_KTXT + (size_t)b*kT*kC;
  const float* vtxt = ws + WS_VTXT + (size_t)b*kT*kC;

  // tasks: WkF (G*T), sk (T), VB (T*H)
  const int nTask = kG*kT + kT + kT*kH;
  for (int task = tid; task < nTask; task += 256) {
    if (task < kG*kT) {
      const int g = task / kT, t = task % kT;
      float acc = 0.f;
      for (int c = 0; c < kC; ++c) acc = fmaf(Wrel[g*kC + c], ktxt[t*kC + c], acc);
      ws[WS_WKF + b*kG*kT + g*kT + t] = acc;
    } else if (task < kG*kT + kT) {
      const int t = task - kG*kT;
      float acc = 0.f;
      for (int c = 0; c < kC; ++c) acc = fmaf(brel[c], ktxt[t*kC + c], acc);
      ws[WS_SK + b*kT + t] = acc;
    } else {
      const int idx = task - kG*kT - kT;
      const int t = idx / kH, h = idx % kH;
      float acc = 0.f;
      for (int c = 0; c < kC; ++c) acc = fmaf(vtxt[t*kC + c], Wbias[c*kH + h], acc);
      ws[WS_VB + b*kT*kH + t*kH + h] = acc;
    }
  }

  if (b == 0) {
    for (int task = tid; task < kG*kH + kH; task += 256) {
      if (task < kG*kH) {
        const int g = task / kH, h = task % kH;
        float acc = 0.f;
        for (int c = 0; c < kC; ++c) acc = fmaf(Wrel[g*kC + c], Wbias[c*kH + h], acc);
        ws[WS_WB1 + g*kH + h] = acc;
      } else {
        const int h = task - kG*kH;
        float acc = bbias[h];
        for (int c = 0; c < kC; ++c) acc = fmaf(brel[c], Wbias[c*kH + h], acc);
        ws[WS_CB + h] = acc;
      }
    }
  }
}

// ---------------------------------------------------------------------------
// Kernel 3: mega kernel. One block per (b, i); thread j in [0,256).
//   geom -> folded scores -> local softmax(T=64) -> bias[h]
//   -> attention logits -> block softmax over j -> alpha.v -> @Wo + bo
// ---------------------------------------------------------------------------
static __global__ __launch_bounds__(256)
void mega_kernel(const float* __restrict__ centers,
                 const float* __restrict__ Wo, const float* __restrict__ bo,
                 const float* __restrict__ ws, float* __restrict__ out)
{
  const int i = blockIdx.x;
  const int b = blockIdx.y;
  const int tid = threadIdx.x;
  const int j = tid;

  __shared__ float s_cj[kN*3];
  __shared__ float s_sj[kN*3];
  __shared__ float s_w[kN][kH];
  __shared__ float s_redm[4][kH];
  __shared__ float s_reds[4][kH];
  __shared__ float s_part[2][kC];
  __shared__ float s_ao[kC];

  {
    const float* cbp = centers + (size_t)(b*kN)*3;
    const float* sbp = ws + WS_SIZES + (size_t)(b*kN)*3;
    for (int idx = tid; idx < kN*3; idx += 256) {
      s_cj[idx] = cbp[idx];
      s_sj[idx] = sbp[idx];
    }
  }
  __syncthreads();

  // ---- geometry features for (i, j) ----
  const float cix = s_cj[i*3+0], ciy = s_cj[i*3+1], ciz = s_cj[i*3+2];
  const float six = s_sj[i*3+0], siy = s_sj[i*3+1], siz = s_sj[i*3+2];

  float g[kG];
  {
    const float dx = s_cj[j*3+0] - cix;
    const float dy = s_cj[j*3+1] - ciy;
    const float dz = s_cj[j*3+2] - ciz;
    const float dist = sqrtf(dx*dx + dy*dy + dz*dz);
    const float horiz = sqrtf(dx*dx + dy*dy);
    g[0] = dx; g[1] = dy; g[2] = dz;
    g[3] = __logf(dist + kEps);
    g[4] = horiz;
    g[5] = dz / (dist + kEps);
    const float sjx = s_sj[j*3+0], sjy = s_sj[j*3+1], sjz = s_sj[j*3+2];
    g[6] = sjx - six; g[7] = sjy - siy; g[8] = sjz - siz;
    g[9]  = sjx / (six + kEps);
    g[10] = sjy / (siy + kEps);
    g[11] = sjz / (siz + kEps);
  }

  // ---- folded language-attention scores (block-uniform operands) ----
  const float* __restrict__ wkf = ws + WS_WKF + b*kG*kT;
  const float* __restrict__ skp = ws + WS_SK  + b*kT;
  const float* __restrict__ vbp = ws + WS_VB  + b*kT*kH;
  const float* __restrict__ wb1 = ws + WS_WB1;
  const float* __restrict__ cbv = ws + WS_CB;

  float sc[kT];
#pragma unroll
  for (int t = 0; t < kT; ++t) sc[t] = skp[t];
#pragma unroll
  for (int gg = 0; gg < kG; ++gg) {
    const float gv = g[gg];
#pragma unroll
    for (int t = 0; t < kT; ++t) sc[t] = fmaf(gv, wkf[gg*kT + t], sc[t]);
  }
  float m = -3.4e38f;
#pragma unroll
  for (int t = 0; t < kT; ++t) { sc[t] *= kInvSqrtC; m = fmaxf(m, sc[t]); }
  float ssum = 0.f;
#pragma unroll
  for (int t = 0; t < kT; ++t) { sc[t] = __expf(sc[t] - m); ssum += sc[t]; }
  const float invSsum = 1.f / ssum;

  // ---- bias[h] = cb + geom.WB1 + (sum_t alpha_t VB[t][h]) ----
  float bias[kH];
#pragma unroll
  for (int h = 0; h < kH; ++h) {
    float acc = 0.f;
#pragma unroll
    for (int t = 0; t < kT; ++t) acc = fmaf(sc[t], vbp[t*kH + h], acc);
    bias[h] = acc * invSsum + cbv[h];
  }
#pragma unroll
  for (int gg = 0; gg < kG; ++gg) {
    const float gv = g[gg];
#pragma unroll
    for (int h = 0; h < kH; ++h) bias[h] = fmaf(gv, wb1[gg*kH + h], bias[h]);
  }

  // ---- attention logits: q_i (uniform) . k_j (per-thread) ----
  const float* __restrict__ qrow = ws + WS_Q + (size_t)(b*kN + i)*kC;
  const float* __restrict__ krow = ws + WS_K + (size_t)(b*kN + j)*kC;
  float lg[kH];
#pragma unroll
  for (int h = 0; h < kH; ++h) {
    float acc = 0.f;
#pragma unroll
    for (int d = 0; d < kD; ++d) acc = fmaf(qrow[h*kD + d], krow[h*kD + d], acc);
    lg[h] = acc * kInvSqrtD + bias[h];
  }

  // ---- softmax over j across the block (4 waves of 64) ----
  const int wave = tid >> 6, lane = tid & 63;
  float mh[kH];
#pragma unroll
  for (int h = 0; h < kH; ++h) {
    float v = lg[h];
#pragma unroll
    for (int off = 32; off >= 1; off >>= 1) v = fmaxf(v, __shfl_xor(v, off, 64));
    mh[h] = v;
  }
  if (lane == 0) {
#pragma unroll
    for (int h = 0; h < kH; ++h) s_redm[wave][h] = mh[h];
  }
  __syncthreads();
#pragma unroll
  for (int h = 0; h < kH; ++h) {
    float v = s_redm[0][h];
#pragma unroll
    for (int w = 1; w < 4; ++w) v = fmaxf(v, s_redm[w][h]);
    mh[h] = v;
  }
  float eh[kH], sumh[kH];
#pragma unroll
  for (int h = 0; h < kH; ++h) {
    eh[h] = __expf(lg[h] - mh[h]);
    float v = eh[h];
#pragma unroll
    for (int off = 32; off >= 1; off >>= 1) v += __shfl_xor(v, off, 64);
    sumh[h] = v;
  }
  if (lane == 0) {
#pragma unroll
    for (int h = 0; h < kH; ++h) s_reds[wave][h] = sumh[h];
  }
  __syncthreads();
#pragma unroll
  for (int h = 0; h < kH; ++h) {
    const float S = s_reds[0][h] + s_reds[1][h] + s_reds[2][h] + s_reds[3][h];
    s_w[j][h] = eh[h] / S;
  }
  __syncthreads();

  // ---- out_row[c] = sum_j w[j][c/32] * v[b][j][c]  (coalesced in c) ----
  {
    const int c = tid & (kC - 1);
    const int half = tid >> 7;
    const int hh = c >> 5;
    const float* __restrict__ vbase = ws + WS_V + (size_t)(b*kN)*kC;
    float acc = 0.f;
#pragma unroll 4
    for (int jj = 0; jj < kN/2; ++jj) {
      const int jr = half*(kN/2) + jj;
      acc = fmaf(s_w[jr][hh], vbase[jr*kC + c], acc);
    }
    s_part[half][c] = acc;
  }
  __syncthreads();
  if (tid < kC) s_ao[tid] = s_part[0][tid] + s_part[1][tid];
  __syncthreads();

  // ---- fused output projection: out = ao @ Wo + bo ----
  if (tid < kC) {
    float acc = bo[tid];
#pragma unroll 8
    for (int d = 0; d < kC; ++d) acc = fmaf(s_ao[d], Wo[d*kC + tid], acc);
    out[(size_t)(b*kN + i)*kC + tid] = acc;
  }
}

// ---------------------------------------------------------------------------
extern "C" void kernel_launch(void* const* d_in, const int* in_sizes, int n_in,
                              void* d_out, int out_size, void* d_ws, size_t ws_size,
                              hipStream_t stream)
{
  (void)in_sizes; (void)n_in; (void)out_size; (void)ws_size;
  const float* feat    = (const float*)d_in[0];
  const float* centers = (const float*)d_in[1];
  const float* corners = (const float*)d_in[2];
  const float* lang    = (const float*)d_in[3];
  const float* Wq   = (const float*)d_in[4];
  const float* bq   = (const float*)d_in[5];
  const float* Wk   = (const float*)d_in[6];
  const float* bk   = (const float*)d_in[7];
  const float* Wv   = (const float*)d_in[8];
  const float* bv   = (const float*)d_in[9];
  const float* Wo   = (const float*)d_in[10];
  const float* bo   = (const float*)d_in[11];
  const float* Wrel = (const float*)d_in[12];
  const float* brel = (const float*)d_in[13];
  const float* Wtk  = (const float*)d_in[14];
  const float* btk  = (const float*)d_in[15];
  const float* Wtv  = (const float*)d_in[16];
  const float* btv  = (const float*)d_in[17];
  const float* Wbias = (const float*)d_in[18];
  const float* bbias = (const float*)d_in[19];

  float* ws  = (float*)d_ws;   // needs ~3.73 MB
  float* out = (float*)d_out;

  proj_kernel<<<dim3(kB*kN + kB*kT), dim3(128), 0, stream>>>(
      feat, lang, Wq, bq, Wk, bk, Wv, bv, Wtk, btk, Wtv, btv, ws);
  fold_kernel<<<dim3(kB), dim3(256), 0, stream>>>(
      corners, Wrel, brel, Wbias, bbias, ws);
  mega_kernel<<<dim3(kN, kB), dim3(256), 0, stream>>>(
      centers, Wo, bo, ws, out);
}

// Round 2
// 214.000 us; speedup vs baseline: 1.0344x; 1.0344x over previous
//
#include <hip/hip_runtime.h>
#include <math.h>

// Problem constants (B, N, C, T, H, G) = (8, 256, 128, 64, 4, 12), D = 32
namespace {
constexpr int kB = 8, kN = 256, kC = 128, kT = 64, kH = 4, kG = 12, kD = 32;
constexpr float kEps = 1e-6f;
constexpr float kInvSqrtC = 0.08838834764831845f;   // 1/sqrt(128)
constexpr float kInvSqrtD = 0.17677669529663687f;   // 1/sqrt(32)

// workspace layout (float offsets)
constexpr int WS_Q     = 0;                          // [b][n][c]
constexpr int WS_K     = WS_Q + kB*kN*kC;            // [b][n][c]
constexpr int WS_V     = WS_K + kB*kN*kC;            // [b][n][c]
constexpr int WS_SIZES = WS_V + kB*kN*kC;            // [b][n][3]
constexpr int WS_KTXT  = WS_SIZES + kB*kN*3;         // [b][t][c]
constexpr int WS_VTXT  = WS_KTXT + kB*kT*kC;         // [b][t][c]
constexpr int WS_WKF   = WS_VTXT + kB*kT*kC;         // [b][g][t] = Wrel @ k_txt^T
constexpr int WS_SK    = WS_WKF + kB*kG*kT;          // [b][t]    = brel . k_txt[t]
constexpr int WS_VB    = WS_SK + kB*kT;              // [b][t][h] = v_txt @ Wbias
constexpr int WS_WB1   = WS_VB + kB*kT*kH;           // [g][h]    = Wrel @ Wbias
constexpr int WS_CB    = WS_WB1 + kG*kH;             // [h]       = brel@Wbias + bbias

constexpr int kRows = 8;                 // rows per proj block
constexpr int kProjQKV  = (kB*kN)/kRows; // 256 blocks
constexpr int kProjTxt  = (kB*kT)/kRows; // 64 blocks
constexpr int kProjSize = (kB*kN)/128;   // 16 blocks (sizes from corners)

// fold tasks: per batch 768 (WkF) + 64 (sk) + 256 (VB) = 1088; global 48+4
constexpr int kTasksPerB = kG*kT + kT + kT*kH;       // 1088
constexpr int kTasksAll  = kB*kTasksPerB;            // 8704
constexpr int kTasksTot  = kTasksAll + kG*kH + kH;   // 8756
constexpr int kFoldBlocks = (kTasksTot + 3) / 4;     // 4 waves / block
}

// ---------------------------------------------------------------------------
// Kernel 1: fused linear projections, 8 rows per block.
//   blocks [0,256)   : q/k/v rows      (feat @ Wq/Wk/Wv + b)
//   blocks [256,320) : k_txt/v_txt rows
//   blocks [320,336) : box sizes from corners
// ---------------------------------------------------------------------------
static __global__ __launch_bounds__(128)
void proj_kernel(const float* __restrict__ feat, const float* __restrict__ lang,
                 const float* __restrict__ corners,
                 const float* __restrict__ Wq, const float* __restrict__ bq,
                 const float* __restrict__ Wk, const float* __restrict__ bk,
                 const float* __restrict__ Wv, const float* __restrict__ bv,
                 const float* __restrict__ Wtk, const float* __restrict__ btk,
                 const float* __restrict__ Wtv, const float* __restrict__ btv,
                 float* __restrict__ ws)
{
  const int blk = blockIdx.x;
  const int c = threadIdx.x;
  __shared__ float rows[kRows][kC];

  if (blk < kProjQKV) {
    const int r0 = blk * kRows;
#pragma unroll
    for (int r = 0; r < kRows; ++r) rows[r][c] = feat[(size_t)(r0+r)*kC + c];
    __syncthreads();
    float aq[kRows], ak[kRows], av[kRows];
#pragma unroll
    for (int r = 0; r < kRows; ++r) { aq[r] = bq[c]; ak[r] = bk[c]; av[r] = bv[c]; }
#pragma unroll 4
    for (int d = 0; d < kC; ++d) {
      const float wq = Wq[d*kC + c], wk = Wk[d*kC + c], wv = Wv[d*kC + c];
#pragma unroll
      for (int r = 0; r < kRows; ++r) {
        const float fv = rows[r][d];
        aq[r] = fmaf(fv, wq, aq[r]);
        ak[r] = fmaf(fv, wk, ak[r]);
        av[r] = fmaf(fv, wv, av[r]);
      }
    }
#pragma unroll
    for (int r = 0; r < kRows; ++r) {
      ws[WS_Q + (r0+r)*kC + c] = aq[r];
      ws[WS_K + (r0+r)*kC + c] = ak[r];
      ws[WS_V + (r0+r)*kC + c] = av[r];
    }
  } else if (blk < kProjQKV + kProjTxt) {
    const int r0 = (blk - kProjQKV) * kRows;   // 0 .. B*T-1
#pragma unroll
    for (int r = 0; r < kRows; ++r) rows[r][c] = lang[(size_t)(r0+r)*kC + c];
    __syncthreads();
    float akt[kRows], avt[kRows];
#pragma unroll
    for (int r = 0; r < kRows; ++r) { akt[r] = btk[c]; avt[r] = btv[c]; }
#pragma unroll 4
    for (int d = 0; d < kC; ++d) {
      const float wk = Wtk[d*kC + c], wv = Wtv[d*kC + c];
#pragma unroll
      for (int r = 0; r < kRows; ++r) {
        const float fv = rows[r][d];
        akt[r] = fmaf(fv, wk, akt[r]);
        avt[r] = fmaf(fv, wv, avt[r]);
      }
    }
#pragma unroll
    for (int r = 0; r < kRows; ++r) {
      ws[WS_KTXT + (r0+r)*kC + c] = akt[r];
      ws[WS_VTXT + (r0+r)*kC + c] = avt[r];
    }
  } else {
    const int n = (blk - kProjQKV - kProjTxt) * 128 + c;  // 0 .. B*N-1
    const float* cp = corners + (size_t)n * 24;
    float mn0 = cp[0], mn1 = cp[1], mn2 = cp[2];
    float mx0 = mn0, mx1 = mn1, mx2 = mn2;
#pragma unroll
    for (int k = 1; k < 8; ++k) {
      const float v0 = cp[k*3+0], v1 = cp[k*3+1], v2 = cp[k*3+2];
      mn0 = fminf(mn0, v0); mx0 = fmaxf(mx0, v0);
      mn1 = fminf(mn1, v1); mx1 = fmaxf(mx1, v1);
      mn2 = fminf(mn2, v2); mx2 = fmaxf(mx2, v2);
    }
    ws[WS_SIZES + n*3 + 0] = mx0 - mn0;
    ws[WS_SIZES + n*3 + 1] = mx1 - mn1;
    ws[WS_SIZES + n*3 + 2] = mx2 - mn2;
  }
}

// ---------------------------------------------------------------------------
// Kernel 2: algebraic folds — one WAVE per 128-length dot product.
// ---------------------------------------------------------------------------
static __global__ __launch_bounds__(256)
void fold_kernel(const float* __restrict__ Wrel, const float* __restrict__ brel,
                 const float* __restrict__ Wbias, const float* __restrict__ bbias,
                 float* __restrict__ ws)
{
  const int task = blockIdx.x * 4 + (threadIdx.x >> 6);
  const int lane = threadIdx.x & 63;
  if (task >= kTasksTot) return;

  const float* x; const float* y; float* outp; float addend = 0.f;
  int ystride4 = 0;   // if nonzero, y is a column of Wbias (stride kH)

  if (task < kTasksAll) {
    const int b = task / kTasksPerB;
    const int tt = task % kTasksPerB;
    const float* ktxt = ws + WS_KTXT + (size_t)b*kT*kC;
    const float* vtxt = ws + WS_VTXT + (size_t)b*kT*kC;
    if (tt < kG*kT) {
      const int g = tt >> 6, t = tt & 63;
      x = Wrel + g*kC; y = ktxt + t*kC;
      outp = ws + WS_WKF + b*kG*kT + g*kT + t;
    } else if (tt < kG*kT + kT) {
      const int t = tt - kG*kT;
      x = brel; y = ktxt + t*kC;
      outp = ws + WS_SK + b*kT + t;
    } else {
      const int idx = tt - kG*kT - kT;
      const int t = idx >> 2, h = idx & 3;
      x = vtxt + t*kC; y = Wbias + h; ystride4 = 1;
      outp = ws + WS_VB + b*kT*kH + t*kH + h;
    }
  } else {
    const int tt = task - kTasksAll;
    if (tt < kG*kH) {
      const int g = tt >> 2, h = tt & 3;
      x = Wrel + g*kC; y = Wbias + h; ystride4 = 1;
      outp = ws + WS_WB1 + g*kH + h;
    } else {
      const int h = tt - kG*kH;
      x = brel; y = Wbias + h; ystride4 = 1;
      addend = bbias[h];
      outp = ws + WS_CB + h;
    }
  }

  float p;
  if (ystride4) {
    p = x[lane]*y[lane*kH] + x[lane+64]*y[(lane+64)*kH];
  } else {
    p = x[lane]*y[lane] + x[lane+64]*y[lane+64];
  }
#pragma unroll
  for (int off = 32; off >= 1; off >>= 1) p += __shfl_xor(p, off, 64);
  if (lane == 0) *outp = p + addend;
}

// ---------------------------------------------------------------------------
// Kernel 3: mega kernel. One block per (b, i); thread j in [0,256).
//   geom -> folded scores (chunked ONLINE softmax, no sc[64] spill)
//   -> bias[h] -> attention logits -> block softmax -> alpha.v -> @Wo + bo
// ---------------------------------------------------------------------------
static __global__ __launch_bounds__(256)
void mega_kernel(const float* __restrict__ centers,
                 const float* __restrict__ Wo, const float* __restrict__ bo,
                 const float* __restrict__ ws, float* __restrict__ out)
{
  const int i = blockIdx.x;
  const int b = blockIdx.y;
  const int tid = threadIdx.x;
  const int j = tid;

  __shared__ float s_cj[kN*3];
  __shared__ float s_sj[kN*3];
  __shared__ float s_w[kN][kH];
  __shared__ float s_redm[4][kH];
  __shared__ float s_reds[4][kH];
  __shared__ float s_part[8][kC];
  __shared__ float s_ao[kC];

  {
    const float* cbp = centers + (size_t)(b*kN)*3;
    const float* sbp = ws + WS_SIZES + (size_t)(b*kN)*3;
    for (int idx = tid; idx < kN*3; idx += 256) {
      s_cj[idx] = cbp[idx];
      s_sj[idx] = sbp[idx];
    }
  }
  __syncthreads();

  // ---- geometry features for (i, j) ----
  const float cix = s_cj[i*3+0], ciy = s_cj[i*3+1], ciz = s_cj[i*3+2];
  const float six = s_sj[i*3+0], siy = s_sj[i*3+1], siz = s_sj[i*3+2];

  float g[kG];
  {
    const float dx = s_cj[j*3+0] - cix;
    const float dy = s_cj[j*3+1] - ciy;
    const float dz = s_cj[j*3+2] - ciz;
    const float dist = sqrtf(dx*dx + dy*dy + dz*dz);
    const float horiz = sqrtf(dx*dx + dy*dy);
    g[0] = dx; g[1] = dy; g[2] = dz;
    g[3] = __logf(dist + kEps);
    g[4] = horiz;
    g[5] = dz / (dist + kEps);
    const float sjx = s_sj[j*3+0], sjy = s_sj[j*3+1], sjz = s_sj[j*3+2];
    g[6] = sjx - six; g[7] = sjy - siy; g[8] = sjz - siz;
    g[9]  = sjx / (six + kEps);
    g[10] = sjy / (siy + kEps);
    g[11] = sjz / (siz + kEps);
  }

  // ---- folded language-attention: chunked online softmax over T=64 ----
  const float* __restrict__ wkf = ws + WS_WKF + b*kG*kT;
  const float* __restrict__ skp = ws + WS_SK  + b*kT;
  const float* __restrict__ vbp = ws + WS_VB  + b*kT*kH;
  const float* __restrict__ wb1 = ws + WS_WB1;
  const float* __restrict__ cbv = ws + WS_CB;

  float m = -1e30f, ssum = 0.f;
  float a0 = 0.f, a1 = 0.f, a2 = 0.f, a3 = 0.f;
#pragma unroll
  for (int c0 = 0; c0 < kT; c0 += 16) {
    float sc[16];
#pragma unroll
    for (int t = 0; t < 16; ++t) sc[t] = skp[c0 + t];
#pragma unroll
    for (int gg = 0; gg < kG; ++gg) {
      const float gv = g[gg];
#pragma unroll
      for (int t = 0; t < 16; ++t) sc[t] = fmaf(gv, wkf[gg*kT + c0 + t], sc[t]);
    }
    float cm = -1e30f;
#pragma unroll
    for (int t = 0; t < 16; ++t) { sc[t] *= kInvSqrtC; cm = fmaxf(cm, sc[t]); }
    const float nm = fmaxf(m, cm);
    const float scale = __expf(m - nm);
    ssum *= scale; a0 *= scale; a1 *= scale; a2 *= scale; a3 *= scale;
#pragma unroll
    for (int t = 0; t < 16; ++t) {
      const float e = __expf(sc[t] - nm);
      ssum += e;
      a0 = fmaf(e, vbp[(c0+t)*kH + 0], a0);
      a1 = fmaf(e, vbp[(c0+t)*kH + 1], a1);
      a2 = fmaf(e, vbp[(c0+t)*kH + 2], a2);
      a3 = fmaf(e, vbp[(c0+t)*kH + 3], a3);
    }
    m = nm;
  }
  const float invSsum = 1.f / ssum;

  float bias[kH];
  bias[0] = a0*invSsum + cbv[0];
  bias[1] = a1*invSsum + cbv[1];
  bias[2] = a2*invSsum + cbv[2];
  bias[3] = a3*invSsum + cbv[3];
#pragma unroll
  for (int gg = 0; gg < kG; ++gg) {
    const float gv = g[gg];
#pragma unroll
    for (int h = 0; h < kH; ++h) bias[h] = fmaf(gv, wb1[gg*kH + h], bias[h]);
  }

  // ---- attention logits: q_i (uniform, scalar loads) . k_j (float4) ----
  const float4* __restrict__ q4 = (const float4*)(ws + WS_Q + (size_t)(b*kN + i)*kC);
  const float4* __restrict__ k4 = (const float4*)(ws + WS_K + (size_t)(b*kN + j)*kC);
  float lg[kH];
#pragma unroll
  for (int h = 0; h < kH; ++h) {
    float acc = 0.f;
#pragma unroll
    for (int d4 = 0; d4 < kD/4; ++d4) {
      const float4 qv = q4[h*(kD/4) + d4];
      const float4 kv = k4[h*(kD/4) + d4];
      acc = fmaf(qv.x, kv.x, acc);
      acc = fmaf(qv.y, kv.y, acc);
      acc = fmaf(qv.z, kv.z, acc);
      acc = fmaf(qv.w, kv.w, acc);
    }
    lg[h] = acc * kInvSqrtD + bias[h];
  }

  // ---- softmax over j across the block (4 waves of 64) ----
  const int wave = tid >> 6, lane = tid & 63;
  float mh[kH];
#pragma unroll
  for (int h = 0; h < kH; ++h) {
    float v = lg[h];
#pragma unroll
    for (int off = 32; off >= 1; off >>= 1) v = fmaxf(v, __shfl_xor(v, off, 64));
    mh[h] = v;
  }
  if (lane == 0) {
#pragma unroll
    for (int h = 0; h < kH; ++h) s_redm[wave][h] = mh[h];
  }
  __syncthreads();
#pragma unroll
  for (int h = 0; h < kH; ++h) {
    float v = s_redm[0][h];
#pragma unroll
    for (int w = 1; w < 4; ++w) v = fmaxf(v, s_redm[w][h]);
    mh[h] = v;
  }
  float eh[kH], sumh[kH];
#pragma unroll
  for (int h = 0; h < kH; ++h) {
    eh[h] = __expf(lg[h] - mh[h]);
    float v = eh[h];
#pragma unroll
    for (int off = 32; off >= 1; off >>= 1) v += __shfl_xor(v, off, 64);
    sumh[h] = v;
  }
  if (lane == 0) {
#pragma unroll
    for (int h = 0; h < kH; ++h) s_reds[wave][h] = sumh[h];
  }
  __syncthreads();
#pragma unroll
  for (int h = 0; h < kH; ++h) {
    const float S = s_reds[0][h] + s_reds[1][h] + s_reds[2][h] + s_reds[3][h];
    s_w[j][h] = eh[h] / S;
  }
  __syncthreads();

  // ---- ao[c] = sum_j w[j][c/32] * v[b][j][c] ; float4 over c, 8 j-groups ----
  {
    const int c4  = tid & 31;      // float4 column index (c = 4*c4)
    const int grp = tid >> 5;      // 8 groups of 32 j's
    const int hh  = c4 >> 3;       // head for these 4 columns
    const float4* __restrict__ v4 = (const float4*)(ws + WS_V + (size_t)(b*kN)*kC);
    float4 acc = make_float4(0.f, 0.f, 0.f, 0.f);
#pragma unroll 4
    for (int jj = 0; jj < 32; ++jj) {
      const int jr = grp*32 + jj;
      const float w = s_w[jr][hh];
      const float4 vv = v4[jr*(kC/4) + c4];
      acc.x = fmaf(w, vv.x, acc.x);
      acc.y = fmaf(w, vv.y, acc.y);
      acc.z = fmaf(w, vv.z, acc.z);
      acc.w = fmaf(w, vv.w, acc.w);
    }
    *(float4*)&s_part[grp][c4*4] = acc;
  }
  __syncthreads();
  if (tid < kC) {
    float v = 0.f;
#pragma unroll
    for (int gp = 0; gp < 8; ++gp) v += s_part[gp][tid];
    s_ao[tid] = v;
  }
  __syncthreads();

  // ---- fused output projection: out = ao @ Wo + bo (split over 2 halves) ----
  {
    const int col = tid & (kC - 1);
    const int seg = tid >> 7;
    float acc = (seg == 0) ? bo[col] : 0.f;
    const int d0 = seg * (kC/2);
#pragma unroll 4
    for (int d = d0; d < d0 + kC/2; ++d) acc = fmaf(s_ao[d], Wo[d*kC + col], acc);
    s_part[seg][col] = acc;
  }
  __syncthreads();
  if (tid < kC) out[(size_t)(b*kN + i)*kC + tid] = s_part[0][tid] + s_part[1][tid];
}

// ---------------------------------------------------------------------------
extern "C" void kernel_launch(void* const* d_in, const int* in_sizes, int n_in,
                              void* d_out, int out_size, void* d_ws, size_t ws_size,
                              hipStream_t stream)
{
  (void)in_sizes; (void)n_in; (void)out_size; (void)ws_size;
  const float* feat    = (const float*)d_in[0];
  const float* centers = (const float*)d_in[1];
  const float* corners = (const float*)d_in[2];
  const float* lang    = (const float*)d_in[3];
  const float* Wq   = (const float*)d_in[4];
  const float* bq   = (const float*)d_in[5];
  const float* Wk   = (const float*)d_in[6];
  const float* bk   = (const float*)d_in[7];
  const float* Wv   = (const float*)d_in[8];
  const float* bv   = (const float*)d_in[9];
  const float* Wo   = (const float*)d_in[10];
  const float* bo   = (const float*)d_in[11];
  const float* Wrel = (const float*)d_in[12];
  const float* brel = (const float*)d_in[13];
  const float* Wtk  = (const float*)d_in[14];
  const float* btk  = (const float*)d_in[15];
  const float* Wtv  = (const float*)d_in[16];
  const float* btv  = (const float*)d_in[17];
  const float* Wbias = (const float*)d_in[18];
  const float* bbias = (const float*)d_in[19];

  float* ws  = (float*)d_ws;   // ~3.73 MB
  float* out = (float*)d_out;

  proj_kernel<<<dim3(kProjQKV + kProjTxt + kProjSize), dim3(128), 0, stream>>>(
      feat, lang, corners, Wq, bq, Wk, bk, Wv, bv, Wtk, btk, Wtv, btv, ws);
  fold_kernel<<<dim3(kFoldBlocks), dim3(256), 0, stream>>>(
      Wrel, brel, Wbias, bbias, ws);
  mega_kernel<<<dim3(kN, kB), dim3(256), 0, stream>>>(
      centers, Wo, bo, ws, out);
}